// Round 1
// baseline (300.793 us; speedup 1.0000x reference)
//
#include <hip/hip_runtime.h>
#include <cstdint>

#define B_ 8
#define N_ 512
#define M_ 512
#define D_ 512
#define F_ 512
#define H_ 8
#define DH_ 64
#define FH_ 64

// K1: Q1[hn][b][d] = gelu_exact(X[b,n,h*64+d] * W_Q_1[h,n,d,d])
__global__ __launch_bounds__(256) void syn_k_q1(const float* __restrict__ X,
                                                const float* __restrict__ W1,
                                                float* __restrict__ Q1p) {
    int idx = blockIdx.x * 256 + threadIdx.x;   // H*N*B*DH = 2M total
    int d  = idx & 63;
    int b  = (idx >> 6) & 7;
    int hn = idx >> 9;                          // h*N + n
    int n  = hn & 511;
    int h  = hn >> 9;
    float x = X[((size_t)(b * N_ + n)) * D_ + h * DH_ + d];
    float w = W1[(size_t)hn * (DH_ * DH_) + d * (DH_ + 1)];   // diagonal
    float v = x * w;
    float g = 0.5f * v * (1.0f + erff(v * 0.70710678118654752440f));
    Q1p[idx] = g;
}

// K2: per (h,n): logits[b][m] = Q1[b,:]·W2[h,n,m,:]; softmax over m; write A.
// Lane layout: b = lane>>3, c = lane&7 (d-chunk of 8). Wave reads one 256B
// W2 row coalesced; shfl_xor over c-bits reduces the dot product.
__global__ __launch_bounds__(256) void syn_k_attn(const float* __restrict__ Q1p,
                                                  const float* __restrict__ W2,
                                                  float* __restrict__ A) {
    int hn = blockIdx.x;
    int h = hn >> 9, n = hn & 511;
    int t = threadIdx.x;
    int wave = t >> 6, lane = t & 63;
    int b = lane >> 3, c = lane & 7;
    __shared__ float logits[8 * 513];           // stride 513: conflict-free

    const float* q1 = Q1p + (size_t)hn * (B_ * DH_) + b * DH_ + c * 8;
    float4 qa = *(const float4*)q1;
    float4 qb = *(const float4*)(q1 + 4);

    const float* w2 = W2 + (size_t)hn * ((size_t)M_ * DH_) + c * 8;
    for (int m = wave; m < M_; m += 4) {
        const float* wr = w2 + (size_t)m * DH_;
        float4 wa = *(const float4*)wr;
        float4 wb = *(const float4*)(wr + 4);
        float acc = wa.x * qa.x + wa.y * qa.y + wa.z * qa.z + wa.w * qa.w
                  + wb.x * qb.x + wb.y * qb.y + wb.z * qb.z + wb.w * qb.w;
        acc += __shfl_xor(acc, 1);
        acc += __shfl_xor(acc, 2);
        acc += __shfl_xor(acc, 4);
        if (c == 0) logits[b * 513 + m] = acc;
    }
    __syncthreads();

    // softmax: wave handles rows b = wave and wave+4
    for (int bb = wave; bb < 8; bb += 4) {
        float v[8];
        #pragma unroll
        for (int i = 0; i < 8; ++i) v[i] = logits[bb * 513 + i * 64 + lane];
        float mx = v[0];
        #pragma unroll
        for (int i = 1; i < 8; ++i) mx = fmaxf(mx, v[i]);
        #pragma unroll
        for (int s = 1; s < 64; s <<= 1) mx = fmaxf(mx, __shfl_xor(mx, s));
        float e[8]; float sum = 0.f;
        #pragma unroll
        for (int i = 0; i < 8; ++i) { e[i] = expf(v[i] - mx); sum += e[i]; }
        #pragma unroll
        for (int s = 1; s < 64; s <<= 1) sum += __shfl_xor(sum, s);
        float inv = 1.0f / sum;
        float* outp = A + ((size_t)(bb * H_ + h) * N_ + n) * M_;
        #pragma unroll
        for (int i = 0; i < 8; ++i) outp[i * 64 + lane] = e[i] * inv;
    }
}

// K3: per (b,h): Y[n,f] = (A[n,:]·Vh[:,f]) * WVdiag[f]. 64x64 output tile,
// A staged transposed [m][n], V natural [m][f]; stride 68 (float4-aligned).
__global__ __launch_bounds__(256) void syn_k_pv(const float* __restrict__ A,
                                                const float* __restrict__ V,
                                                const float* __restrict__ WV,
                                                float* __restrict__ Y) {
    int bh = blockIdx.y;
    int b = bh >> 3, h = bh & 7;
    int n0 = blockIdx.x * 64;
    int t = threadIdx.x;
    int tx = t & 15, ty = t >> 4;
    __shared__ float Alds[64 * 68];   // [k=m][r=n]
    __shared__ float Vlds[64 * 68];   // [k=m][f]
    float acc[4][4] = {};
    const float* Abase = A + ((size_t)bh * N_ + n0) * M_;
    const float* Vbase = V + (size_t)b * M_ * F_ + h * FH_;
    for (int m0 = 0; m0 < M_; m0 += 64) {
        #pragma unroll
        for (int it = 0; it < 4; ++it) {
            int e = t * 4 + it * 1024;
            int r = e >> 6, k = e & 63;
            float4 a4 = *(const float4*)(Abase + (size_t)r * M_ + m0 + k);
            Alds[(k + 0) * 68 + r] = a4.x;
            Alds[(k + 1) * 68 + r] = a4.y;
            Alds[(k + 2) * 68 + r] = a4.z;
            Alds[(k + 3) * 68 + r] = a4.w;
            float4 v4 = *(const float4*)(Vbase + (size_t)(m0 + r) * F_ + k);
            *(float4*)&Vlds[r * 68 + k] = v4;
        }
        __syncthreads();
        #pragma unroll 4
        for (int k = 0; k < 64; ++k) {
            float4 a4 = *(const float4*)&Alds[k * 68 + ty * 4];
            float4 v4 = *(const float4*)&Vlds[k * 68 + tx * 4];
            float ar[4] = {a4.x, a4.y, a4.z, a4.w};
            float vr[4] = {v4.x, v4.y, v4.z, v4.w};
            #pragma unroll
            for (int i = 0; i < 4; ++i)
                #pragma unroll
                for (int j = 0; j < 4; ++j)
                    acc[i][j] += ar[i] * vr[j];
        }
        __syncthreads();
    }
    float s[4];
    #pragma unroll
    for (int j = 0; j < 4; ++j)
        s[j] = WV[(size_t)h * (FH_ * FH_) + (tx * 4 + j) * (FH_ + 1)];
    #pragma unroll
    for (int i = 0; i < 4; ++i) {
        int row = n0 + ty * 4 + i;
        float4 o = make_float4(acc[i][0] * s[0], acc[i][1] * s[1],
                               acc[i][2] * s[2], acc[i][3] * s[3]);
        *(float4*)(Y + ((size_t)(b * N_ + row)) * F_ + h * FH_ + tx * 4) = o;
    }
}

// K4: out[r,f'] = Σ_k Y[r,k]·Ow[f',k] + Ob[f'];  r over B*N.
__global__ __launch_bounds__(256) void syn_k_out(const float* __restrict__ Yg,
                                                 const float* __restrict__ Ow,
                                                 const float* __restrict__ Ob,
                                                 float* __restrict__ out) {
    int r0 = blockIdx.y * 64;
    int f0 = blockIdx.x * 64;
    int t = threadIdx.x;
    int tx = t & 15, ty = t >> 4;
    __shared__ float Ylds[64 * 68];   // [k][r]
    __shared__ float Wlds[64 * 68];   // [k][f']
    float acc[4][4] = {};
    for (int k0 = 0; k0 < F_; k0 += 64) {
        #pragma unroll
        for (int it = 0; it < 4; ++it) {
            int e = t * 4 + it * 1024;
            int r = e >> 6, k = e & 63;
            float4 y4 = *(const float4*)(Yg + (size_t)(r0 + r) * F_ + k0 + k);
            Ylds[(k + 0) * 68 + r] = y4.x;
            Ylds[(k + 1) * 68 + r] = y4.y;
            Ylds[(k + 2) * 68 + r] = y4.z;
            Ylds[(k + 3) * 68 + r] = y4.w;
            float4 w4 = *(const float4*)(Ow + (size_t)(f0 + r) * F_ + k0 + k);
            Wlds[(k + 0) * 68 + r] = w4.x;
            Wlds[(k + 1) * 68 + r] = w4.y;
            Wlds[(k + 2) * 68 + r] = w4.z;
            Wlds[(k + 3) * 68 + r] = w4.w;
        }
        __syncthreads();
        #pragma unroll 4
        for (int k = 0; k < 64; ++k) {
            float4 y4 = *(const float4*)&Ylds[k * 68 + ty * 4];
            float4 w4 = *(const float4*)&Wlds[k * 68 + tx * 4];
            float yr[4] = {y4.x, y4.y, y4.z, y4.w};
            float wr[4] = {w4.x, w4.y, w4.z, w4.w};
            #pragma unroll
            for (int i = 0; i < 4; ++i)
                #pragma unroll
                for (int j = 0; j < 4; ++j)
                    acc[i][j] += yr[i] * wr[j];
        }
        __syncthreads();
    }
    float bb[4];
    #pragma unroll
    for (int j = 0; j < 4; ++j) bb[j] = Ob[f0 + tx * 4 + j];
    #pragma unroll
    for (int i = 0; i < 4; ++i) {
        int row = r0 + ty * 4 + i;
        float4 o = make_float4(acc[i][0] + bb[0], acc[i][1] + bb[1],
                               acc[i][2] + bb[2], acc[i][3] + bb[3]);
        *(float4*)(out + (size_t)row * F_ + f0 + tx * 4) = o;
    }
}

extern "C" void kernel_launch(void* const* d_in, const int* in_sizes, int n_in,
                              void* d_out, int out_size, void* d_ws, size_t ws_size,
                              hipStream_t stream) {
    const float* X  = (const float*)d_in[0];
    const float* V  = (const float*)d_in[1];
    const float* W1 = (const float*)d_in[2];
    const float* W2 = (const float*)d_in[3];
    const float* WV = (const float*)d_in[4];
    const float* Ow = (const float*)d_in[5];
    const float* Ob = (const float*)d_in[6];
    float* out = (float*)d_out;

    float* ws  = (float*)d_ws;
    float* Q1p = ws;                                        // H*N*B*DH = 2M floats
    float* A   = Q1p + (size_t)H_ * N_ * B_ * DH_;          // B*H*N*M  = 16.78M floats
    float* Y   = A + (size_t)B_ * H_ * N_ * M_;             // B*N*F    = 2M floats

    syn_k_q1<<<(H_ * N_ * B_ * DH_) / 256, 256, 0, stream>>>(X, W1, Q1p);
    syn_k_attn<<<H_ * N_, 256, 0, stream>>>(Q1p, W2, A);
    syn_k_pv<<<dim3(N_ / 64, B_ * H_), 256, 0, stream>>>(A, V, WV, Y);
    syn_k_out<<<dim3(F_ / 64, (B_ * N_) / 64), 256, 0, stream>>>(Y, Ow, Ob, out);
}